// Round 8
// baseline (44.238 us; speedup 1.0000x reference)
//
#include <hip/hip_runtime.h>

#define C_DIM 512
#define G_DIM 128
#define ROW_STRIDE 1536   // 3*C
#define CGROUPS 16        // 32-channel slices -> grid = 128*16 = 2048 blocks (8/CU)
#define NTHREADS 256      // 8 channel-threads (x float4 = 32 ch) x 32 row-replicas
#define CGT 8             // channel threads per block
#define RG 32             // row replicas per block
#define UNROLL 8

typedef float f4 __attribute__((ext_vector_type(4)));

__device__ __forceinline__ f4 ldnt(const float* p) {
    return __builtin_nontemporal_load(reinterpret_cast<const f4*>(p));
}

__device__ __forceinline__ void acc4(f4& s, f4& m, f4 v) {
    s += v;
    m[0] = fmaxf(m[0], v[0]); m[1] = fmaxf(m[1], v[1]);
    m[2] = fmaxf(m[2], v[2]); m[3] = fmaxf(m[3], v[3]);
}

// Race-free serial binary search (per thread; redundant across threads but
// the prologue is TLP-hidden — proven by round 6's null result). The
// cooperative bracket search had a read/update race that shifted segment
// bounds by a row on some timings -> removed.
__device__ __forceinline__ int lower_bound(const int* __restrict__ a, int n, int v) {
    int lo = 0, hi = n;
    while (lo < hi) {
        int mid = (lo + hi) >> 1;
        if (a[mid] < v) lo = mid + 1; else hi = mid;
    }
    return lo;
}

// Owner-block design: block (g, cb) owns output row g, channels
// [cb*32, cb*32+32). Blocks are g-major so the 16 siblings of a graph
// stream the same rows co-temporally (DRAM page locality).
__global__ __launch_bounds__(NTHREADS) void pool_owner_kernel(
        const float* __restrict__ x, const int* __restrict__ batch,
        float* __restrict__ out, int N) {
    const int g   = blockIdx.x >> 4;   // / CGROUPS  (g-major: siblings adjacent)
    const int cb  = blockIdx.x & 15;   // % CGROUPS
    const int tid = threadIdx.x;
    const int cg  = tid & (CGT - 1);   // channel thread: owns 4 floats
    const int rg  = tid >> 3;          // row replica 0..31

    const int start = lower_bound(batch, N, g);
    const int end   = lower_bound(batch, N, g + 1);
    const int cnt   = end - start;

    f4 s = {0.f, 0.f, 0.f, 0.f};
    f4 m = {-INFINITY, -INFINITY, -INFINITY, -INFINITY};

    const float* base = x + (size_t)start * C_DIM + cb * 32 + cg * 4;

    // Branch-free stream: rows rg, rg+32, ...; unroll-8 keeps 8 independent
    // 16 B loads in flight per thread (256 rows per outer iteration).
    int r = rg;
    for (; r + (UNROLL - 1) * RG < cnt; r += UNROLL * RG) {
        f4 v[UNROLL];
#pragma unroll
        for (int j = 0; j < UNROLL; ++j)
            v[j] = ldnt(base + (size_t)(r + j * RG) * C_DIM);
#pragma unroll
        for (int j = 0; j < UNROLL; ++j) acc4(s, m, v[j]);
    }
    for (; r < cnt; r += RG)
        acc4(s, m, ldnt(base + (size_t)r * C_DIM));

    // Reduce across the 32 row replicas in LDS (tree, conflict-free).
    __shared__ f4 ls[2][RG][CGT];   // 2*32*8*16B = 8 KB
    ls[0][rg][cg] = s;
    ls[1][rg][cg] = m;
    __syncthreads();
#pragma unroll
    for (int off = RG / 2; off >= 1; off >>= 1) {
        if (rg < off) {
            f4 sa = ls[0][rg][cg], s2 = ls[0][rg + off][cg];
            f4 ma = ls[1][rg][cg], m2 = ls[1][rg + off][cg];
            sa += s2;
            ma[0] = fmaxf(ma[0], m2[0]); ma[1] = fmaxf(ma[1], m2[1]);
            ma[2] = fmaxf(ma[2], m2[2]); ma[3] = fmaxf(ma[3], m2[3]);
            ls[0][rg][cg] = sa;
            ls[1][rg][cg] = ma;
        }
        __syncthreads();
    }

    if (rg == 0) {
        f4 fs = ls[0][0][cg];
        f4 fm = ls[1][0][cg];
        const float inv = 1.0f / (float)max(cnt, 1);
        if (cnt == 0) fm = (f4){0.f, 0.f, 0.f, 0.f};  // torch_geometric: 0 for empty
        f4 mean = fs * inv;
        float* row = out + (size_t)g * ROW_STRIDE + cb * 32 + cg * 4;
        *reinterpret_cast<f4*>(row)        = mean;
        *reinterpret_cast<f4*>(row + 512)  = fm;
        *reinterpret_cast<f4*>(row + 1024) = fs;
    }
}

extern "C" void kernel_launch(void* const* d_in, const int* in_sizes, int n_in,
                              void* d_out, int out_size, void* d_ws, size_t ws_size,
                              hipStream_t stream) {
    const float* x     = (const float*)d_in[0];
    const int*   batch = (const int*)d_in[1];
    float* out = (float*)d_out;
    int N = in_sizes[0] / C_DIM;

    pool_owner_kernel<<<G_DIM * CGROUPS, NTHREADS, 0, stream>>>(x, batch, out, N);
}

// Round 9
// 38.775 us; speedup vs baseline: 1.1409x; 1.1409x over previous
//
#include <hip/hip_runtime.h>

#define C_DIM 512
#define G_DIM 128
#define ROW_STRIDE 1536   // 3*C
#define CGROUPS 4         // 128-channel slices -> grid = 128*4 = 512 blocks
#define NTHREADS 512      // 32 channel-threads (x float4 = 128 ch) x 16 row-replicas
#define CGT 32            // channel threads per block
#define RG 16             // row replicas per block
#define UNROLL 4

typedef float f4 __attribute__((ext_vector_type(4)));

__device__ __forceinline__ void acc4(f4& s, f4& m, f4 v) {
    s += v;
    m[0] = fmaxf(m[0], v[0]); m[1] = fmaxf(m[1], v[1]);
    m[2] = fmaxf(m[2], v[2]); m[3] = fmaxf(m[3], v[3]);
}

// Race-free serial binary search (redundant per thread; prologue is
// TLP-hidden — proven null in round 6).
__device__ __forceinline__ int lower_bound(const int* __restrict__ a, int n, int v) {
    int lo = 0, hi = n;
    while (lo < hi) {
        int mid = (lo + hi) >> 1;
        if (a[mid] < v) lo = mid + 1; else hi = mid;
    }
    return lo;
}

// Owner-block design: block (g, cb) owns output row g, channels
// [cb*128, cb*128+128) = 512 B contiguous per row. g-major block order keeps
// the 4 siblings of a graph streaming the same rows co-temporally.
// Measured granularity landscape: 128 B/row = 44.2 us, 256 B/row = 39.9 us,
// this probes 512 B/row at identical waves/CU (16).
__global__ __launch_bounds__(NTHREADS) void pool_owner_kernel(
        const float* __restrict__ x, const int* __restrict__ batch,
        float* __restrict__ out, int N) {
    const int g   = blockIdx.x >> 2;   // / CGROUPS  (g-major)
    const int cb  = blockIdx.x & 3;    // % CGROUPS
    const int tid = threadIdx.x;
    const int cg  = tid & (CGT - 1);   // channel thread: owns 4 floats
    const int rg  = tid >> 5;          // row replica 0..15

    const int start = lower_bound(batch, N, g);
    const int end   = lower_bound(batch, N, g + 1);
    const int cnt   = end - start;

    f4 s = {0.f, 0.f, 0.f, 0.f};
    f4 m = {-INFINITY, -INFINITY, -INFINITY, -INFINITY};

    const float* base = x + (size_t)start * C_DIM + cb * 128 + cg * 4;

    // Branch-free stream: rows rg, rg+16, ...; unroll-4 keeps 4 independent
    // 16 B loads in flight per thread.
    int r = rg;
    for (; r + (UNROLL - 1) * RG < cnt; r += UNROLL * RG) {
        f4 v[UNROLL];
#pragma unroll
        for (int j = 0; j < UNROLL; ++j)
            v[j] = *reinterpret_cast<const f4*>(base + (size_t)(r + j * RG) * C_DIM);
#pragma unroll
        for (int j = 0; j < UNROLL; ++j) acc4(s, m, v[j]);
    }
    for (; r < cnt; r += RG)
        acc4(s, m, *reinterpret_cast<const f4*>(base + (size_t)r * C_DIM));

    // Reduce across the 16 row replicas in LDS (tree, conflict-free).
    __shared__ f4 ls[2][RG][CGT];   // 2*16*32*16B = 16 KB
    ls[0][rg][cg] = s;
    ls[1][rg][cg] = m;
    __syncthreads();
#pragma unroll
    for (int off = RG / 2; off >= 1; off >>= 1) {
        if (rg < off) {
            f4 sa = ls[0][rg][cg], s2 = ls[0][rg + off][cg];
            f4 ma = ls[1][rg][cg], m2 = ls[1][rg + off][cg];
            sa += s2;
            ma[0] = fmaxf(ma[0], m2[0]); ma[1] = fmaxf(ma[1], m2[1]);
            ma[2] = fmaxf(ma[2], m2[2]); ma[3] = fmaxf(ma[3], m2[3]);
            ls[0][rg][cg] = sa;
            ls[1][rg][cg] = ma;
        }
        __syncthreads();
    }

    if (rg == 0) {
        f4 fs = ls[0][0][cg];
        f4 fm = ls[1][0][cg];
        const float inv = 1.0f / (float)max(cnt, 1);
        if (cnt == 0) fm = (f4){0.f, 0.f, 0.f, 0.f};  // torch_geometric: 0 for empty
        f4 mean = fs * inv;
        float* row = out + (size_t)g * ROW_STRIDE + cb * 128 + cg * 4;
        *reinterpret_cast<f4*>(row)        = mean;
        *reinterpret_cast<f4*>(row + 512)  = fm;
        *reinterpret_cast<f4*>(row + 1024) = fs;
    }
}

extern "C" void kernel_launch(void* const* d_in, const int* in_sizes, int n_in,
                              void* d_out, int out_size, void* d_ws, size_t ws_size,
                              hipStream_t stream) {
    const float* x     = (const float*)d_in[0];
    const int*   batch = (const int*)d_in[1];
    float* out = (float*)d_out;
    int N = in_sizes[0] / C_DIM;

    pool_owner_kernel<<<G_DIM * CGROUPS, NTHREADS, 0, stream>>>(x, batch, out, N);
}